// Round 12
// baseline (196.184 us; speedup 1.0000x reference)
//
#include <hip/hip_runtime.h>

#define B_N 32
#define S_N 1024

typedef __attribute__((ext_vector_type(8))) short sh8;
typedef __attribute__((ext_vector_type(4))) short sh4;
typedef __attribute__((ext_vector_type(4))) float f4;

#define AS1 __attribute__((address_space(1)))
#define AS3 __attribute__((address_space(3)))

__device__ __forceinline__ short f2bf(float f) {
  unsigned u = __builtin_bit_cast(unsigned, f);
  u += 0x7fff + ((u >> 16) & 1);
  return (short)(u >> 16);
}
__device__ __forceinline__ float dot4(f4 a, f4 w) {
  return a.x * w.x + a.y * w.y + a.z * w.z + a.w * w.w;
}

// ---------- Phase 1: ONE kernel, all projections (independent jobs, one launch)
// blocks 0..511: Q proj (DIN=128) + qmask | 512..1023: K proj + kmask
// 1024..1535: qctx (DIN=64) | 1536..2047: kctx | 2048..3071: V halves (transposed)
template <int DIN>
__device__ __forceinline__ void dev_proj(const float* __restrict__ in,
                                         const float* __restrict__ W,
                                         const float* __restrict__ bias,
                                         short* __restrict__ out,
                                         float* __restrict__ mask, int blk, char* ldsb) {
  constexpr int NS = DIN / 4;
  f4* w_lds = (f4*)ldsb;               // [64][NS+1]
  f4* a_lds = w_lds + 64 * (NS + 1);   // [64][NS+1]
  const int tid = threadIdx.x;
  for (int e = tid; e < 64 * NS; e += 256) w_lds[(e / NS) * (NS + 1) + (e % NS)] = ((const f4*)W)[e];
  const f4* inb = (const f4*)(in + (size_t)blk * 64 * DIN);
  for (int e = tid; e < 64 * NS; e += 256) a_lds[(e / NS) * (NS + 1) + (e % NS)] = inb[e];
  __syncthreads();
  if (mask && tid < 64) {
    float s = 0.f;
#pragma unroll
    for (int d = 0; d < NS; ++d) {
      f4 a = a_lds[tid * (NS + 1) + d];
      s += fabsf(a.x) + fabsf(a.y) + fabsf(a.z) + fabsf(a.w);
    }
    mask[blk * 64 + tid] = (s != 0.f) ? 1.f : 0.f;
  }
  const int c1 = tid & 15, r4 = tid >> 4;
  float acc[4][4];
#pragma unroll
  for (int i = 0; i < 4; ++i)
#pragma unroll
    for (int k = 0; k < 4; ++k) acc[i][k] = 0.f;
#pragma unroll
  for (int d = 0; d < NS; ++d) {
    f4 w[4], a[4];
#pragma unroll
    for (int k = 0; k < 4; ++k) w[k] = w_lds[(c1 + k * 16) * (NS + 1) + d];
#pragma unroll
    for (int i = 0; i < 4; ++i) a[i] = a_lds[(r4 * 4 + i) * (NS + 1) + d];
#pragma unroll
    for (int i = 0; i < 4; ++i)
#pragma unroll
      for (int k = 0; k < 4; ++k) acc[i][k] += dot4(a[i], w[k]);
  }
  const size_t r0 = (size_t)blk * 64;
#pragma unroll
  for (int i = 0; i < 4; ++i)
#pragma unroll
    for (int k = 0; k < 4; ++k)
      out[(r0 + r4 * 4 + i) * 64 + c1 + k * 16] = f2bf(acc[i][k] + bias[c1 + k * 16]);
}

__device__ __forceinline__ void dev_proj_v(const float* __restrict__ in,
                                           const float* __restrict__ W,
                                           const float* __restrict__ bias,
                                           short* __restrict__ vt, int blk, char* ldsb) {
  constexpr int NS = 32;
  f4* w_lds = (f4*)ldsb;
  f4* a_lds = w_lds + 64 * (NS + 1);
  short* tile = (short*)(a_lds + 64 * (NS + 1));  // [64][72]
  const int tid = threadIdx.x;
  const int c1 = tid & 15, r4 = tid >> 4;
  for (int e = tid; e < 64 * NS; e += 256) w_lds[(e >> 5) * (NS + 1) + (e & 31)] = ((const f4*)W)[e];
  const f4* inb = (const f4*)(in + (size_t)blk * 64 * 128);
  for (int e = tid; e < 64 * NS; e += 256) a_lds[(e >> 5) * (NS + 1) + (e & 31)] = inb[e];
  __syncthreads();
  float acc[4][4];
#pragma unroll
  for (int i = 0; i < 4; ++i)
#pragma unroll
    for (int k = 0; k < 4; ++k) acc[i][k] = 0.f;
#pragma unroll
  for (int d = 0; d < NS; ++d) {
    f4 w[4], a[4];
#pragma unroll
    for (int k = 0; k < 4; ++k) w[k] = w_lds[(c1 + k * 16) * (NS + 1) + d];
#pragma unroll
    for (int i = 0; i < 4; ++i) a[i] = a_lds[(r4 * 4 + i) * (NS + 1) + d];
#pragma unroll
    for (int i = 0; i < 4; ++i)
#pragma unroll
      for (int k = 0; k < 4; ++k) acc[i][k] += dot4(a[i], w[k]);
  }
#pragma unroll
  for (int i = 0; i < 4; ++i)
#pragma unroll
    for (int k = 0; k < 4; ++k)
      tile[(c1 + k * 16) * 72 + r4 * 4 + i] = f2bf(acc[i][k] + bias[c1 + k * 16]);
  __syncthreads();
  const int b = (blk * 64) / S_N, s0 = (blk * 64) % S_N;
  const int j = tid >> 2, seg = tid & 3;
  sh8 v0 = *(sh8*)&tile[j * 72 + seg * 16];
  sh8 v1 = *(sh8*)&tile[j * 72 + seg * 16 + 8];
  short* dst = vt + ((size_t)(b * 128 + j)) * S_N + s0 + seg * 16;
  *(sh8*)dst = v0;
  *(sh8*)(dst + 8) = v1;
}

__global__ __launch_bounds__(256) void phase1_kernel(
    const float* __restrict__ queries_it, const float* __restrict__ keys_it,
    const float* __restrict__ queries_ctx, const float* __restrict__ keys_ctx,
    const float* __restrict__ Wq_it, const float* __restrict__ bq_it,
    const float* __restrict__ Wk_it, const float* __restrict__ bk_it,
    const float* __restrict__ Wq_ctx, const float* __restrict__ bq_ctx,
    const float* __restrict__ Wk_ctx, const float* __restrict__ bk_ctx,
    const float* __restrict__ Wv, const float* __restrict__ bv,
    short* __restrict__ qit, short* __restrict__ kit,
    short* __restrict__ qctx, short* __restrict__ kctx, short* __restrict__ vt,
    float* __restrict__ qmask, float* __restrict__ kmask) {
  __shared__ __align__(16) char ulds[76800];
  const int bid = blockIdx.x;
  if (bid < 512) {
    dev_proj<128>(queries_it, Wq_it, bq_it, qit, qmask, bid, ulds);
  } else if (bid < 1024) {
    dev_proj<128>(keys_it, Wk_it, bk_it, kit, kmask, bid - 512, ulds);
  } else if (bid < 1536) {
    dev_proj<64>(queries_ctx, Wq_ctx, bq_ctx, qctx, nullptr, bid - 1024, ulds);
  } else if (bid < 2048) {
    dev_proj<64>(keys_ctx, Wk_ctx, bk_ctx, kctx, nullptr, bid - 1536, ulds);
  } else {
    const int v = bid - 2048, ph = v >> 9, blk = v & 511;
    dev_proj_v(keys_it, Wv + ph * 64 * 128, bv + ph * 64, vt + (size_t)ph * 64 * S_N, blk, ulds);
  }
}

// ---------- Phase 2: fused attention, double-buffered pipeline (R11, unchanged) ----------
__global__ __launch_bounds__(256, 2) void attn_kernel(
    const short* __restrict__ qit, const short* __restrict__ kit,
    const short* __restrict__ qctx, const short* __restrict__ kctx,
    const short* __restrict__ vt,     // [B,128,S] bf16
    const float* __restrict__ noise,  // [B,2,S,S]
    const float* __restrict__ sigma,  // [B,2]
    const float* __restrict__ qmask, const float* __restrict__ kmask,  // [B,S]
    const float* __restrict__ qin,    // queries_it [B,S,128]
    const float* __restrict__ W1, const float* __restrict__ b1,
    const float* __restrict__ W2, const float* __restrict__ b2,
    float* __restrict__ out) {
  __shared__ __align__(16) char bufs[2][32768];
  __shared__ float kml[1024];
  __shared__ float lsum_lds[4][2][16];

  const int tid = threadIdx.x;
  const int wave = tid >> 6, lane = tid & 63;
  const int bid = blockIdx.x;
  const int wg = ((bid & 7) << 6) | (bid >> 3);  // XCD swizzle (512 % 8 == 0)
  const int b = wg >> 4, qt = wg & 15;
  const int qblk = qt * 64;
  const int qbase = qblk + wave * 16;
  const int col = lane & 15, grp = lane >> 4;
  const int sw_key = col & 7;

  const float w100 = W1[0], w101 = W1[1], w110 = W1[2], w111 = W1[3];
  const float bb10 = b1[0], bb11 = b1[1];
  const float sc = 0.125f;
  const float w200 = W2[0] * sc, w201 = W2[1] * sc, w210 = W2[2] * sc, w211 = W2[3] * sc;
  const float bb20 = b2[0] * sc, bb21 = b2[1] * sc;
  float sg0 = sigma[b * 2 + 0]; sg0 *= sg0;
  float sg1 = sigma[b * 2 + 1]; sg1 *= sg1;

  const int qrow = qbase + col;
  sh8 aqit[2], aqctx[2];
#pragma unroll
  for (int t = 0; t < 2; ++t) {
    aqit[t] = *(const sh8*)(qit + ((size_t)(b * S_N + qrow)) * 64 + grp * 8 + t * 32);
    aqctx[t] = *(const sh8*)(qctx + ((size_t)(b * S_N + qrow)) * 64 + grp * 8 + t * 32);
  }

  f4 acc[2][4];
#pragma unroll
  for (int h = 0; h < 2; ++h)
#pragma unroll
    for (int dt = 0; dt < 4; ++dt) acc[h][dt] = (f4)0.f;
  float rs0 = 0.f, rs1 = 0.f;

  const float* nz_g = noise + (size_t)(b * 2) * S_N * S_N;
  const short* kit_g = kit + (size_t)b * S_N * 64;
  const short* kctx_g = kctx + (size_t)b * S_N * 64;
  const short* vt_g = vt + (size_t)b * 128 * S_N;

  for (int i = tid; i < 1024; i += 256) kml[i] = kmask[(size_t)b * S_N + i];

  auto STAGE = [&](char* buf, int kc) {
    {
      const int u = wave * 64 + lane, row = u >> 3, sl = u & 7;
      const short* g = kit_g + (size_t)(kc + row) * 64 + ((sl ^ (row & 7)) << 3);
      __builtin_amdgcn_global_load_lds((const AS1 unsigned*)g, (AS3 unsigned*)(buf + wave * 1024), 16, 0, 0);
    }
    {
      const int u = wave * 64 + lane, row = u >> 3, sl = u & 7;
      const short* g = kctx_g + (size_t)(kc + row) * 64 + ((sl ^ (row & 7)) << 3);
      __builtin_amdgcn_global_load_lds((const AS1 unsigned*)g, (AS3 unsigned*)(buf + 4096 + wave * 1024), 16, 0, 0);
    }
#pragma unroll
    for (int i = 0; i < 2; ++i) {
      const int un = 2 * wave + i;
      const int v = un * 64 + lane, d = v >> 2, sl = v & 3;
      const short* g = vt_g + (size_t)d * S_N + kc + ((sl ^ (d & 3)) << 3);
      __builtin_amdgcn_global_load_lds((const AS1 unsigned*)g, (AS3 unsigned*)(buf + 8192 + un * 1024), 16, 0, 0);
    }
#pragma unroll
    for (int i = 0; i < 4; ++i) {
      const int un = 4 * wave + i;
      const int n = un * 64 + lane, r16 = n >> 3, head = r16 >> 6, q = r16 & 63, sl = n & 7;
      const float* g = nz_g + (size_t)head * S_N * S_N + (size_t)(qblk + q) * S_N + kc + ((sl ^ (q & 7)) << 2);
      __builtin_amdgcn_global_load_lds((const AS1 unsigned*)g, (AS3 unsigned*)(buf + 16384 + un * 1024), 16, 0, 0);
    }
  };

  STAGE(bufs[0], 0);  // prologue

#pragma unroll 1
  for (int kcc = 0; kcc < 32; ++kcc) {
    const int kc = kcc * 32;
    char* cur = bufs[0] + (size_t)(kcc & 1) * 32768;
    char* nxt = bufs[0] + (size_t)((kcc & 1) ^ 1) * 32768;
    __syncthreads();
    if (kcc + 1 < 32) STAGE(nxt, kc + 32);

    const short* Kb = (const short*)cur;
    const short* Cb = (const short*)(cur + 4096);
    const short* Vb = (const short*)(cur + 8192);
    const float* Nb = (const float*)(cur + 16384);

    f4 sit[2], sctx[2];
#pragma unroll
    for (int kt = 0; kt < 2; ++kt) {
      const int krow = kt * 16 + col;
      sit[kt] = (f4)0.f;
      sctx[kt] = (f4)0.f;
#pragma unroll
      for (int t = 0; t < 2; ++t) {
        const int so = ((grp + 4 * t) ^ sw_key) * 8;
        sh8 bk = *(const sh8*)&Kb[krow * 64 + so];
        sit[kt] = __builtin_amdgcn_mfma_f32_16x16x32_bf16(bk, aqit[t], sit[kt], 0, 0, 0);
        sh8 bc = *(const sh8*)&Cb[krow * 64 + so];
        sctx[kt] = __builtin_amdgcn_mfma_f32_16x16x32_bf16(bc, aqctx[t], sctx[kt], 0, 0, 0);
      }
    }
    asm volatile("" ::: "memory");
    __builtin_amdgcn_s_barrier();
    asm volatile("" ::: "memory");

    short* Pb = (short*)cur;
    const int qrl = wave * 16 + col;
    const int prow0 = wave * 32 + col;
#pragma unroll
    for (int kt = 0; kt < 2; ++kt) {
      const int nsl = ((kt * 4 + grp) ^ sw_key) * 4;
      f4 n0 = *(const f4*)&Nb[(size_t)qrl * 32 + nsl];
      f4 n1 = *(const f4*)&Nb[(size_t)(64 + qrl) * 32 + nsl];
      f4 km = *(const f4*)&kml[kc + kt * 16 + grp * 4];
      sh4 po, pc;
#pragma unroll
      for (int r = 0; r < 4; ++r) {
        float x0 = fmaf(n0[r], sg0, sit[kt][r]);
        float x1 = fmaf(n1[r], sg1, sctx[kt][r]);
        float h0 = fmaxf(fmaf(w101, x1, fmaf(w100, x0, bb10)), 0.f);
        float h1 = fmaxf(fmaf(w111, x1, fmaf(w110, x0, bb11)), 0.f);
        float L0 = fmaf(w201, h1, fmaf(w200, h0, bb20));
        float L1 = fmaf(w211, h1, fmaf(w210, h0, bb21));
        float p0 = __expf(L0) * km[r];
        float p1 = __expf(L1) * km[r];
        rs0 += p0;
        rs1 += p1;
        po[r] = f2bf(p0);
        pc[r] = f2bf(p1);
      }
      const int sl8 = kt * 2 + (grp >> 1);
      const int off0 = ((sl8 ^ (prow0 & 3)) * 8) + (grp & 1) * 4;
      const int prow1 = prow0 + 16;
      const int off1 = ((sl8 ^ (prow1 & 3)) * 8) + (grp & 1) * 4;
      *(sh4*)&Pb[prow0 * 32 + off0] = po;
      *(sh4*)&Pb[prow1 * 32 + off1] = pc;
    }
#pragma unroll
    for (int h = 0; h < 2; ++h) {
      const int prow = wave * 32 + h * 16 + col;
      sh8 pa = *(const sh8*)&Pb[prow * 32 + ((grp ^ (prow & 3)) * 8)];
#pragma unroll
      for (int dt = 0; dt < 4; ++dt) {
        const int drow = h * 64 + dt * 16 + col;
        sh8 bv = *(const sh8*)&Vb[drow * 32 + ((grp ^ (drow & 3)) * 8)];
        acc[h][dt] = __builtin_amdgcn_mfma_f32_16x16x32_bf16(pa, bv, acc[h][dt], 0, 0, 0);
      }
    }
  }

  rs0 += __shfl_xor(rs0, 16); rs0 += __shfl_xor(rs0, 32);
  rs1 += __shfl_xor(rs1, 16); rs1 += __shfl_xor(rs1, 32);
  if (lane < 16) {
    lsum_lds[wave][0][col] = rs0;
    lsum_lds[wave][1][col] = rs1;
  }
  __syncthreads();
  f4 ls0 = *(const f4*)&lsum_lds[wave][0][grp * 4];
  f4 ls1 = *(const f4*)&lsum_lds[wave][1][grp * 4];
  f4 qm4 = *(const f4*)(qmask + (size_t)b * S_N + qbase + grp * 4);
#pragma unroll
  for (int h = 0; h < 2; ++h)
#pragma unroll
    for (int dt = 0; dt < 4; ++dt)
#pragma unroll
      for (int r = 0; r < 4; ++r) {
        const float s2 = qm4[r] / (h ? ls1[r] : ls0[r]);
        const size_t o = ((size_t)(b * S_N + qbase + grp * 4 + r)) * 128 + h * 64 + dt * 16 + col;
        out[o] = acc[h][dt][r] * s2 + qin[o];
      }
}

extern "C" void kernel_launch(void* const* d_in, const int* in_sizes, int n_in,
                              void* d_out, int out_size, void* d_ws, size_t ws_size,
                              hipStream_t stream) {
  const float* queries_it = (const float*)d_in[0];
  const float* queries_ctx = (const float*)d_in[1];
  const float* keys_it = (const float*)d_in[2];
  const float* keys_ctx = (const float*)d_in[3];
  const float* sigma = (const float*)d_in[4];
  const float* noise = (const float*)d_in[5];
  const float* Wq_it = (const float*)d_in[6];
  const float* bq_it = (const float*)d_in[7];
  const float* Wk_it = (const float*)d_in[8];
  const float* bk_it = (const float*)d_in[9];
  const float* Wq_ctx = (const float*)d_in[10];
  const float* bq_ctx = (const float*)d_in[11];
  const float* Wk_ctx = (const float*)d_in[12];
  const float* bk_ctx = (const float*)d_in[13];
  const float* Wv = (const float*)d_in[14];
  const float* bv = (const float*)d_in[15];
  const float* W1 = (const float*)d_in[16];
  const float* b1 = (const float*)d_in[17];
  const float* W2 = (const float*)d_in[18];
  const float* b2 = (const float*)d_in[19];
  float* out = (float*)d_out;

  char* ws = (char*)d_ws;
  short* qit = (short*)(ws);                    // 4 MB
  short* kit = (short*)(ws + (4ull << 20));     // 4 MB
  short* qctx = (short*)(ws + (8ull << 20));    // 4 MB
  short* kctx = (short*)(ws + (12ull << 20));   // 4 MB
  short* vt = (short*)(ws + (16ull << 20));     // 8 MB  [B,128,S]
  float* qmask = (float*)(ws + (24ull << 20));  // 128 KB
  float* kmask = (float*)(ws + (24ull << 20) + (size_t)B_N * S_N * 4);

  phase1_kernel<<<dim3(3072), 256, 0, stream>>>(
      queries_it, keys_it, queries_ctx, keys_ctx,
      Wq_it, bq_it, Wk_it, bk_it, Wq_ctx, bq_ctx, Wk_ctx, bk_ctx, Wv, bv,
      qit, kit, qctx, kctx, vt, qmask, kmask);

  attn_kernel<<<dim3(B_N * (S_N / 64)), 256, 0, stream>>>(
      qit, kit, qctx, kctx, vt, noise, sigma, qmask, kmask, queries_it,
      W1, b1, W2, b2, out);
}

// Round 13
// 185.189 us; speedup vs baseline: 1.0594x; 1.0594x over previous
//
#include <hip/hip_runtime.h>

#define B_N 32
#define S_N 1024

typedef __attribute__((ext_vector_type(8))) short sh8;
typedef __attribute__((ext_vector_type(4))) short sh4;
typedef __attribute__((ext_vector_type(4))) float f4;

#define AS1 __attribute__((address_space(1)))
#define AS3 __attribute__((address_space(3)))

__device__ __forceinline__ short f2bf(float f) {
  unsigned u = __builtin_bit_cast(unsigned, f);
  u += 0x7fff + ((u >> 16) & 1);
  return (short)(u >> 16);
}
__device__ __forceinline__ float dot4(f4 a, f4 w) {
  return a.x * w.x + a.y * w.y + a.z * w.z + a.w * w.w;
}

#if defined(__has_builtin)
#if __has_builtin(__builtin_amdgcn_mfma_f32_16x16x16bf16_1k)
#define HAVE_MFMA16 1
#endif
#endif
__device__ __forceinline__ f4 mfma16(sh4 a, sh4 b, f4 c) {
#ifdef HAVE_MFMA16
  return __builtin_amdgcn_mfma_f32_16x16x16bf16_1k(a, b, c, 0, 0, 0);
#else
  asm volatile("v_mfma_f32_16x16x16_bf16 %0, %1, %2, %0\n\ts_nop 7\n\ts_nop 7"
               : "+v"(c) : "v"(a), "v"(b));
  return c;
#endif
}

// ---------- Phase 1a: Q projection + query mask ----------
__global__ __launch_bounds__(256) void proj_q_fused(
    const float* __restrict__ in, const float* __restrict__ W,
    const float* __restrict__ bias, short* __restrict__ out,
    float* __restrict__ qm) {
  __shared__ f4 w_lds[64][33];
  __shared__ f4 a_lds[64][33];
  const int tid = threadIdx.x;
  for (int e = tid; e < 64 * 32; e += 256) w_lds[e >> 5][e & 31] = ((const f4*)W)[e];
  const f4* inb = (const f4*)(in + (size_t)blockIdx.x * 64 * 128);
  for (int e = tid; e < 64 * 32; e += 256) a_lds[e >> 5][e & 31] = inb[e];
  __syncthreads();
  if (tid < 64) {
    float s = 0.f;
#pragma unroll
    for (int d = 0; d < 32; ++d) {
      f4 a = a_lds[tid][d];
      s += fabsf(a.x) + fabsf(a.y) + fabsf(a.z) + fabsf(a.w);
    }
    qm[blockIdx.x * 64 + tid] = (s != 0.f) ? 1.f : 0.f;
  }
  const int c1 = tid & 15, r4 = tid >> 4;
  float acc[4][4];
#pragma unroll
  for (int i = 0; i < 4; ++i)
#pragma unroll
    for (int k = 0; k < 4; ++k) acc[i][k] = 0.f;
#pragma unroll
  for (int d = 0; d < 32; ++d) {
    f4 w[4], a[4];
#pragma unroll
    for (int k = 0; k < 4; ++k) w[k] = w_lds[c1 + k * 16][d];
#pragma unroll
    for (int i = 0; i < 4; ++i) a[i] = a_lds[r4 * 4 + i][d];
#pragma unroll
    for (int i = 0; i < 4; ++i)
#pragma unroll
      for (int k = 0; k < 4; ++k) acc[i][k] += dot4(a[i], w[k]);
  }
  const size_t r0 = (size_t)blockIdx.x * 64;
#pragma unroll
  for (int i = 0; i < 4; ++i)
#pragma unroll
    for (int k = 0; k < 4; ++k)
      out[(r0 + r4 * 4 + i) * 64 + c1 + k * 16] = f2bf(acc[i][k] + bias[c1 + k * 16]);
}

// ---------- Phase 1b: K projection + V (both halves, transposed) + key mask ----------
__global__ __launch_bounds__(256) void proj_k_fused(
    const float* __restrict__ in,
    const float* __restrict__ Wk, const float* __restrict__ bk_,
    const float* __restrict__ Wv, const float* __restrict__ bv_,
    short* __restrict__ kit, short* __restrict__ vt, float* __restrict__ km) {
  __shared__ f4 w_lds[64][33];
  __shared__ f4 a_lds[64][33];
  __shared__ short tile[64][72];
  const int tid = threadIdx.x;
  const int c1 = tid & 15, r4 = tid >> 4;
  const f4* inb = (const f4*)(in + (size_t)blockIdx.x * 64 * 128);
  for (int e = tid; e < 64 * 32; e += 256) a_lds[e >> 5][e & 31] = inb[e];
  for (int e = tid; e < 64 * 32; e += 256) w_lds[e >> 5][e & 31] = ((const f4*)Wk)[e];
  __syncthreads();
  if (tid < 64) {
    float s = 0.f;
#pragma unroll
    for (int d = 0; d < 32; ++d) {
      f4 a = a_lds[tid][d];
      s += fabsf(a.x) + fabsf(a.y) + fabsf(a.z) + fabsf(a.w);
    }
    km[blockIdx.x * 64 + tid] = (s != 0.f) ? 1.f : 0.f;
  }
  {
    float acc[4][4];
#pragma unroll
    for (int i = 0; i < 4; ++i)
#pragma unroll
      for (int k = 0; k < 4; ++k) acc[i][k] = 0.f;
#pragma unroll
    for (int d = 0; d < 32; ++d) {
      f4 w[4], a[4];
#pragma unroll
      for (int k = 0; k < 4; ++k) w[k] = w_lds[c1 + k * 16][d];
#pragma unroll
      for (int i = 0; i < 4; ++i) a[i] = a_lds[r4 * 4 + i][d];
#pragma unroll
      for (int i = 0; i < 4; ++i)
#pragma unroll
        for (int k = 0; k < 4; ++k) acc[i][k] += dot4(a[i], w[k]);
    }
    const size_t r0 = (size_t)blockIdx.x * 64;
#pragma unroll
    for (int i = 0; i < 4; ++i)
#pragma unroll
      for (int k = 0; k < 4; ++k)
        kit[(r0 + r4 * 4 + i) * 64 + c1 + k * 16] = f2bf(acc[i][k] + bk_[c1 + k * 16]);
  }
  const int b = (blockIdx.x * 64) / S_N, s0 = (blockIdx.x * 64) % S_N;
#pragma unroll 1
  for (int ph = 0; ph < 2; ++ph) {
    __syncthreads();
    for (int e = tid; e < 64 * 32; e += 256)
      w_lds[e >> 5][e & 31] = ((const f4*)Wv)[ph * 64 * 32 + e];
    __syncthreads();
    float acc[4][4];
#pragma unroll
    for (int i = 0; i < 4; ++i)
#pragma unroll
      for (int k = 0; k < 4; ++k) acc[i][k] = 0.f;
#pragma unroll
    for (int d = 0; d < 32; ++d) {
      f4 w[4], a[4];
#pragma unroll
      for (int k = 0; k < 4; ++k) w[k] = w_lds[c1 + k * 16][d];
#pragma unroll
      for (int i = 0; i < 4; ++i) a[i] = a_lds[r4 * 4 + i][d];
#pragma unroll
      for (int i = 0; i < 4; ++i)
#pragma unroll
        for (int k = 0; k < 4; ++k) acc[i][k] += dot4(a[i], w[k]);
    }
#pragma unroll
    for (int i = 0; i < 4; ++i)
#pragma unroll
      for (int k = 0; k < 4; ++k)
        tile[c1 + k * 16][r4 * 4 + i] = f2bf(acc[i][k] + bv_[ph * 64 + c1 + k * 16]);
    __syncthreads();
    const int j = tid >> 2, seg = tid & 3;
    sh8 v0 = *(sh8*)&tile[j][seg * 16];
    sh8 v1 = *(sh8*)&tile[j][seg * 16 + 8];
    short* dst = vt + ((size_t)(b * 128 + ph * 64 + j)) * S_N + s0 + seg * 16;
    *(sh8*)dst = v0;
    *(sh8*)(dst + 8) = v1;
  }
}

// ---------- Phase 1c: ctx projections (DIN=64) ----------
__global__ __launch_bounds__(256) void proj_ctx(
    const float* __restrict__ in, const float* __restrict__ W,
    const float* __restrict__ bias, short* __restrict__ out) {
  constexpr int NS = 16;
  __shared__ f4 w_lds[64][NS + 1];
  __shared__ f4 a_lds[64][NS + 1];
  const int tid = threadIdx.x;
  for (int e = tid; e < 64 * NS; e += 256) w_lds[e / NS][e % NS] = ((const f4*)W)[e];
  const f4* inb = (const f4*)(in + (size_t)blockIdx.x * 64 * 64);
  for (int e = tid; e < 64 * NS; e += 256) a_lds[e / NS][e % NS] = inb[e];
  __syncthreads();
  const int c1 = tid & 15, r4 = tid >> 4;
  float acc[4][4];
#pragma unroll
  for (int i = 0; i < 4; ++i)
#pragma unroll
    for (int k = 0; k < 4; ++k) acc[i][k] = 0.f;
#pragma unroll
  for (int d = 0; d < NS; ++d) {
    f4 w[4], a[4];
#pragma unroll
    for (int k = 0; k < 4; ++k) w[k] = w_lds[c1 + k * 16][d];
#pragma unroll
    for (int i = 0; i < 4; ++i) a[i] = a_lds[r4 * 4 + i][d];
#pragma unroll
    for (int i = 0; i < 4; ++i)
#pragma unroll
      for (int k = 0; k < 4; ++k) acc[i][k] += dot4(a[i], w[k]);
  }
  const size_t r0 = (size_t)blockIdx.x * 64;
#pragma unroll
  for (int i = 0; i < 4; ++i)
#pragma unroll
    for (int k = 0; k < 4; ++k)
      out[(r0 + r4 * 4 + i) * 64 + c1 + k * 16] = f2bf(acc[i][k] + bias[c1 + k * 16]);
}

// ---------- Phase 2: fused attention, depth-3 counted-vmcnt pipeline ----------
// Grid 512 (XCD-swizzled), 4 waves, 64 q-rows/block, 64 chunks of 16 keys.
// 4 LDS buffers (16KB each: K 2K | kctx 2K | V 4K | noise 8K); 3 chunks
// permanently in flight. Per iter: {vmcnt(8) -> s_barrier -> STAGE(k+3) ->
// compute(k)} — each wave proves ITS OWN stage(k) landed (vmcnt counts 4
// loads/wave/chunk) BEFORE the barrier; the barrier then proves it block-wide
// and licenses overwriting buf[(k-1)&3]. Dummy modulo-staging at the tail
// keeps the vmcnt count uniform. 16-key chunks make QK^T's C-layout
// (q=col, k=grp*4+r) EXACTLY the A-fragment of mfma_f32_16x16x16_bf16, so
// P feeds PV straight from registers: no P-LDS, no mid barrier.
// Logits ~1e-3 by construction => fixed softmax max 0 is safe.
__global__ __launch_bounds__(256, 2) void attn_kernel(
    const short* __restrict__ qit, const short* __restrict__ kit,
    const short* __restrict__ qctx, const short* __restrict__ kctx,
    const short* __restrict__ vt,     // [B,128,S] bf16
    const float* __restrict__ noise,  // [B,2,S,S]
    const float* __restrict__ sigma,  // [B,2]
    const float* __restrict__ qmask, const float* __restrict__ kmask,  // [B,S]
    const float* __restrict__ qin,    // queries_it [B,S,128]
    const float* __restrict__ W1, const float* __restrict__ b1,
    const float* __restrict__ W2, const float* __restrict__ b2,
    float* __restrict__ out) {
  __shared__ __align__(16) char bufs[4][16384];
  __shared__ float kml[1024];
  __shared__ float lsum_lds[4][2][16];

  const int tid = threadIdx.x;
  const int wave = tid >> 6, lane = tid & 63;
  const int bid = blockIdx.x;
  const int wg = ((bid & 7) << 6) | (bid >> 3);  // XCD swizzle (512 % 8 == 0)
  const int b = wg >> 4, qt = wg & 15;
  const int qblk = qt * 64;
  const int qbase = qblk + wave * 16;
  const int col = lane & 15, grp = lane >> 4;
  const int swk = col & 7;

  const float w100 = W1[0], w101 = W1[1], w110 = W1[2], w111 = W1[3];
  const float bb10 = b1[0], bb11 = b1[1];
  const float sc = 0.125f;
  const float w200 = W2[0] * sc, w201 = W2[1] * sc, w210 = W2[2] * sc, w211 = W2[3] * sc;
  const float bb20 = b2[0] * sc, bb21 = b2[1] * sc;
  float sg0 = sigma[b * 2 + 0]; sg0 *= sg0;
  float sg1 = sigma[b * 2 + 1]; sg1 *= sg1;

  // Q fragments (B-operand of swapped QK^T): q = col, d = grp*8 + t*32
  const int qrow = qbase + col;
  sh8 aqit[2], aqctx[2];
#pragma unroll
  for (int t = 0; t < 2; ++t) {
    aqit[t] = *(const sh8*)(qit + ((size_t)(b * S_N + qrow)) * 64 + grp * 8 + t * 32);
    aqctx[t] = *(const sh8*)(qctx + ((size_t)(b * S_N + qrow)) * 64 + grp * 8 + t * 32);
  }

  f4 acc[2][4];
#pragma unroll
  for (int h = 0; h < 2; ++h)
#pragma unroll
    for (int dt = 0; dt < 4; ++dt) acc[h][dt] = (f4)0.f;
  float rs0 = 0.f, rs1 = 0.f;

  const float* nz_g = noise + (size_t)(b * 2) * S_N * S_N;
  const short* kit_g = kit + (size_t)b * S_N * 64;
  const short* kctx_g = kctx + (size_t)b * S_N * 64;
  const short* vt_g = vt + (size_t)b * 128 * S_N;

  for (int i = tid; i < 1024; i += 256) kml[i] = kmask[(size_t)b * S_N + i];

  // STAGE one 16-key chunk: exactly 4 global_load_lds (1KB each) PER WAVE.
  auto STAGE = [&](char* buf, int kc) {
    if (wave == 0) {  // K + kctx: [16 rows][8 slots of 8 shorts], swz sl^(row&7)
#pragma unroll
      for (int j = 0; j < 2; ++j) {
        const int u = j * 64 + lane, row = u >> 3, sl = u & 7;
        const size_t off = (size_t)(kc + row) * 64 + ((sl ^ (row & 7)) << 3);
        __builtin_amdgcn_global_load_lds((const AS1 unsigned*)(kit_g + off),
                                         (AS3 unsigned*)(buf + j * 1024), 16, 0, 0);
        __builtin_amdgcn_global_load_lds((const AS1 unsigned*)(kctx_g + off),
                                         (AS3 unsigned*)(buf + 2048 + j * 1024), 16, 0, 0);
      }
    } else if (wave == 1) {  // V: [128 d][2 slots of 8 shorts], swz sl^(d&1)
#pragma unroll
      for (int j = 0; j < 4; ++j) {
        const int u = j * 64 + lane, d = u >> 1, sl = u & 1;
        const short* g = vt_g + (size_t)d * S_N + kc + ((sl ^ (d & 1)) << 3);
        __builtin_amdgcn_global_load_lds((const AS1 unsigned*)g,
                                         (AS3 unsigned*)(buf + 4096 + j * 1024), 16, 0, 0);
      }
    } else {  // noise: [2 head][64 q][4 slots of f4], swz sl^(q&3)
#pragma unroll
      for (int j = 0; j < 4; ++j) {
        const int un = (wave - 2) * 4 + j;
        const int u = un * 64 + lane, r = u >> 2, head = r >> 6, q = r & 63, sl = u & 3;
        const float* g = nz_g + (size_t)head * S_N * S_N + (size_t)(qblk + q) * S_N + kc +
                         ((sl ^ (q & 3)) << 2);
        __builtin_amdgcn_global_load_lds((const AS1 unsigned*)g,
                                         (AS3 unsigned*)(buf + 8192 + un * 1024), 16, 0, 0);
      }
    }
  };

  STAGE(bufs[0], 0);
  STAGE(bufs[1], 16);
  STAGE(bufs[2], 32);

#pragma unroll 1
  for (int k = 0; k < 64; ++k) {
    // own stage(k) complete (outstanding <= stages k+1,k+2 = 8)...
    asm volatile("s_waitcnt vmcnt(8)" ::: "memory");
    __builtin_amdgcn_sched_barrier(0);
    // ...then block-wide: everyone's stage(k) landed, chunk k-1 fully consumed
    __builtin_amdgcn_s_barrier();
    STAGE(bufs[(k + 3) & 3], ((k + 3) & 63) * 16);  // overwrite buf[(k-1)&3]

    const char* cur = bufs[k & 3];
    const short* Kb = (const short*)cur;
    const short* Cb = (const short*)(cur + 2048);
    const short* Vb = (const short*)(cur + 4096);
    const float* Nb = (const float*)(cur + 8192);

    // --- QK^T (swapped): C = S^T, key = grp*4+r, q = col
    f4 sit = (f4)0.f, sctx = (f4)0.f;
#pragma unroll
    for (int t = 0; t < 2; ++t) {
      const int so = ((grp + 4 * t) ^ swk) * 8;
      sh8 bk = *(const sh8*)&Kb[col * 64 + so];
      sit = __builtin_amdgcn_mfma_f32_16x16x32_bf16(bk, aqit[t], sit, 0, 0, 0);
      sh8 bc = *(const sh8*)&Cb[col * 64 + so];
      sctx = __builtin_amdgcn_mfma_f32_16x16x32_bf16(bc, aqctx[t], sctx, 0, 0, 0);
    }
    // --- MLP + exp + mask; P stays in registers (PV A-fragment layout!)
    const int qrl = wave * 16 + col;
    const int nso = (grp ^ (col & 3)) << 2;
    f4 n0 = *(const f4*)&Nb[qrl * 16 + nso];
    f4 n1 = *(const f4*)&Nb[(64 + qrl) * 16 + nso];
    f4 km = *(const f4*)&kml[k * 16 + grp * 4];
    sh4 po, pc;
#pragma unroll
    for (int r = 0; r < 4; ++r) {
      float x0 = fmaf(n0[r], sg0, sit[r]);
      float x1 = fmaf(n1[r], sg1, sctx[r]);
      float h0 = fmaxf(fmaf(w101, x1, fmaf(w100, x0, bb10)), 0.f);
      float h1 = fmaxf(fmaf(w111, x1, fmaf(w110, x0, bb11)), 0.f);
      float L0 = fmaf(w201, h1, fmaf(w200, h0, bb20));
      float L1 = fmaf(w211, h1, fmaf(w210, h0, bb21));
      float p0 = __expf(L0) * km[r];
      float p1 = __expf(L1) * km[r];
      rs0 += p0;
      rs1 += p1;
      po[r] = f2bf(p0);
      pc[r] = f2bf(p1);
    }
    // --- PV: A = P (registers), B = V fragment (sh4: k = grp*4..+3)
#pragma unroll
    for (int h = 0; h < 2; ++h) {
      const sh4 pa = h ? pc : po;
#pragma unroll
      for (int dt = 0; dt < 4; ++dt) {
        const int drow = h * 64 + dt * 16 + col;
        const int phys = (grp >> 1) ^ (drow & 1);
        sh4 bv = *(const sh4*)&Vb[drow * 16 + phys * 8 + (grp & 1) * 4];
        acc[h][dt] = mfma16(pa, bv, acc[h][dt]);
      }
    }
  }

  // sum-exp: reduce over the 4 lanes sharing q=col, redistribute via LDS
  rs0 += __shfl_xor(rs0, 16); rs0 += __shfl_xor(rs0, 32);
  rs1 += __shfl_xor(rs1, 16); rs1 += __shfl_xor(rs1, 32);
  if (lane < 16) {
    lsum_lds[wave][0][col] = rs0;
    lsum_lds[wave][1][col] = rs1;
  }
  __syncthreads();
  f4 ls0 = *(const f4*)&lsum_lds[wave][0][grp * 4];
  f4 ls1 = *(const f4*)&lsum_lds[wave][1][grp * 4];
  f4 qm4 = *(const f4*)(qmask + (size_t)b * S_N + qbase + grp * 4);
#pragma unroll
  for (int h = 0; h < 2; ++h)
#pragma unroll
    for (int dt = 0; dt < 4; ++dt)
#pragma unroll
      for (int r = 0; r < 4; ++r) {
        const float s2 = qm4[r] / (h ? ls1[r] : ls0[r]);
        const size_t o = ((size_t)(b * S_N + qbase + grp * 4 + r)) * 128 + h * 64 + dt * 16 + col;
        out[o] = acc[h][dt][r] * s2 + qin[o];
      }
}

extern "C" void kernel_launch(void* const* d_in, const int* in_sizes, int n_in,
                              void* d_out, int out_size, void* d_ws, size_t ws_size,
                              hipStream_t stream) {
  const float* queries_it = (const float*)d_in[0];
  const float* queries_ctx = (const float*)d_in[1];
  const float* keys_it = (const float*)d_in[2];
  const float* keys_ctx = (const float*)d_in[3];
  const float* sigma = (const float*)d_in[4];
  const float* noise = (const float*)d_in[5];
  const float* Wq_it = (const float*)d_in[6];
  const float* bq_it = (const float*)d_in[7];
  const float* Wk_it = (const float*)d_in[8];
  const float* bk_it = (const float*)d_in[9];
  const float* Wq_ctx = (const float*)d_in[10];
  const float* bq_ctx = (const float*)d_in[11];
  const float* Wk_ctx = (const float*)d_in[12];
  const float* bk_ctx = (const float*)d_in[13];
  const float* Wv = (const float*)d_in[14];
  const float* bv = (const float*)d_in[15];
  const float* W1 = (const float*)d_in[16];
  const float* b1 = (const float*)d_in[17];
  const float* W2 = (const float*)d_in[18];
  const float* b2 = (const float*)d_in[19];
  float* out = (float*)d_out;

  char* ws = (char*)d_ws;
  short* qit = (short*)(ws);                    // 4 MB
  short* kit = (short*)(ws + (4ull << 20));     // 4 MB
  short* qctx = (short*)(ws + (8ull << 20));    // 4 MB
  short* kctx = (short*)(ws + (12ull << 20));   // 4 MB
  short* vt = (short*)(ws + (16ull << 20));     // 8 MB  [B,128,S]
  float* qmask = (float*)(ws + (24ull << 20));  // 128 KB
  float* kmask = (float*)(ws + (24ull << 20) + (size_t)B_N * S_N * 4);

  const int NR = B_N * S_N;
  proj_q_fused<<<dim3(NR / 64), 256, 0, stream>>>(queries_it, Wq_it, bq_it, qit, qmask);
  proj_k_fused<<<dim3(NR / 64), 256, 0, stream>>>(keys_it, Wk_it, bk_it, Wv, bv, kit, vt, kmask);
  proj_ctx<<<dim3(NR / 64), 256, 0, stream>>>(queries_ctx, Wq_ctx, bq_ctx, qctx);
  proj_ctx<<<dim3(NR / 64), 256, 0, stream>>>(keys_ctx, Wk_ctx, bk_ctx, kctx);

  attn_kernel<<<dim3(B_N * (S_N / 64)), 256, 0, stream>>>(
      qit, kit, qctx, kctx, vt, noise, sigma, qmask, kmask, queries_it,
      W1, b1, W2, b2, out);
}

// Round 14
// 126.988 us; speedup vs baseline: 1.5449x; 1.4583x over previous
//
#include <hip/hip_runtime.h>

#define B_N 32
#define S_N 1024

typedef __attribute__((ext_vector_type(8))) short sh8;
typedef __attribute__((ext_vector_type(4))) short sh4;
typedef __attribute__((ext_vector_type(4))) float f4;

#define AS1 __attribute__((address_space(1)))
#define AS3 __attribute__((address_space(3)))

__device__ __forceinline__ short f2bf(float f) {
  unsigned u = __builtin_bit_cast(unsigned, f);
  u += 0x7fff + ((u >> 16) & 1);
  return (short)(u >> 16);
}

#if defined(__has_builtin)
#if __has_builtin(__builtin_amdgcn_mfma_f32_16x16x16bf16_1k)
#define HAVE_MFMA16 1
#endif
#endif
__device__ __forceinline__ f4 mfma16(sh4 a, sh4 b, f4 c) {
#ifdef HAVE_MFMA16
  return __builtin_amdgcn_mfma_f32_16x16x16bf16_1k(a, b, c, 0, 0, 0);
#else
  asm volatile("v_mfma_f32_16x16x16_bf16 %0, %1, %2, %0\n\ts_nop 7\n\ts_nop 7"
               : "+v"(c) : "v"(a), "v"(b));
  return c;
#endif
}

// convert 8 consecutive f32 at src to sh8, also return abs-sum
__device__ __forceinline__ sh8 cvt8(const float* src, float& s) {
  f4 x0 = *(const f4*)src;
  f4 x1 = *(const f4*)(src + 4);
  sh8 v;
#pragma unroll
  for (int i = 0; i < 4; ++i) {
    v[i] = f2bf(x0[i]);
    v[4 + i] = f2bf(x1[i]);
    s += fabsf(x0[i]) + fabsf(x1[i]);
  }
  return v;
}

// ---------- Phase 1 (MFMA): generic 128-row x 64-col projection ----------
// in [*][DIN] f32 -> out [*][64] bf16 ; optional row mask (sign of |row| sum).
// LDS tiles staged as bf16 with XOR slot-swizzle (slot ^ row&(NSL-1)); A-frag
// row=lane&15, k=grp*8+t*32; B-frag col=lane&15; C col=lane&15,row=grp*4+reg
// (same verified layouts as the attn kernel).
template <int DIN, bool MASK>
__global__ __launch_bounds__(256) void proj_mfma(
    const float* __restrict__ in, const float* __restrict__ W,
    const float* __restrict__ bias, short* __restrict__ out,
    float* __restrict__ mask) {
  constexpr int NSL = DIN / 8;  // sh8 slots per row
  constexpr int KT = DIN / 32;  // MFMA k-chunks
  __shared__ __align__(16) short a_t[128 * DIN];
  __shared__ __align__(16) short w_t[64 * DIN];
  const int tid = threadIdx.x;
  const int wave = tid >> 6, lane = tid & 63;
  const int col = lane & 15, grp = lane >> 4;
  const size_t r0g = (size_t)blockIdx.x * 128;

  // stage input (coalesced f32 reads -> bf16 swizzled LDS) + optional mask
#pragma unroll
  for (int t = 0; t < 128 * NSL / 256; ++t) {
    const int u = t * 256 + tid, row = u / NSL, sl = u % NSL;
    float s = 0.f;
    sh8 v = cvt8(in + (r0g + row) * DIN + sl * 8, s);
    *(sh8*)&a_t[(row * NSL + (sl ^ (row & (NSL - 1)))) * 8] = v;
    if (MASK) {  // 16 slots/row live in one 16-lane group
      s += __shfl_xor(s, 1); s += __shfl_xor(s, 2);
      s += __shfl_xor(s, 4); s += __shfl_xor(s, 8);
      if ((lane & 15) == 0) mask[r0g + row] = (s != 0.f) ? 1.f : 0.f;
    }
  }
#pragma unroll
  for (int t = 0; t < 64 * NSL / 256; ++t) {
    const int u = t * 256 + tid, row = u / NSL, sl = u % NSL;
    float s = 0.f;
    sh8 v = cvt8(W + (size_t)row * DIN + sl * 8, s);
    *(sh8*)&w_t[(row * NSL + (sl ^ (row & (NSL - 1)))) * 8] = v;
  }
  __syncthreads();

  const int r0 = wave * 32;
  sh8 a[2][KT];
#pragma unroll
  for (int ri = 0; ri < 2; ++ri)
#pragma unroll
    for (int t = 0; t < KT; ++t) {
      const int row = r0 + ri * 16 + col;
      a[ri][t] = *(const sh8*)&a_t[(row * NSL + ((grp + 4 * t) ^ (row & (NSL - 1)))) * 8];
    }
  f4 acc[2][4];
#pragma unroll
  for (int ri = 0; ri < 2; ++ri)
#pragma unroll
    for (int jt = 0; jt < 4; ++jt) acc[ri][jt] = (f4)0.f;
#pragma unroll
  for (int jt = 0; jt < 4; ++jt) {
    const int j = jt * 16 + col;
    sh8 bw[KT];
#pragma unroll
    for (int t = 0; t < KT; ++t)
      bw[t] = *(const sh8*)&w_t[(j * NSL + ((grp + 4 * t) ^ (j & (NSL - 1)))) * 8];
#pragma unroll
    for (int ri = 0; ri < 2; ++ri)
#pragma unroll
      for (int t = 0; t < KT; ++t)
        acc[ri][jt] = __builtin_amdgcn_mfma_f32_16x16x32_bf16(a[ri][t], bw[t], acc[ri][jt], 0, 0, 0);
  }
#pragma unroll
  for (int jt = 0; jt < 4; ++jt) {
    const float bj = bias[jt * 16 + col];
#pragma unroll
    for (int ri = 0; ri < 2; ++ri)
#pragma unroll
      for (int r = 0; r < 4; ++r)
        out[(r0g + r0 + ri * 16 + grp * 4 + r) * 64 + jt * 16 + col] = f2bf(acc[ri][jt][r] + bj);
  }
}

// ---------- Phase 1 (MFMA): K projection + V (128 cols, transposed) + kmask ----------
__global__ __launch_bounds__(256) void proj_k_mfma(
    const float* __restrict__ in, const float* __restrict__ Wk, const float* __restrict__ bk_,
    const float* __restrict__ Wv, const float* __restrict__ bv_,
    short* __restrict__ kit, short* __restrict__ vt, float* __restrict__ km) {
  __shared__ __align__(16) char ulds[65536];
  short* a_t = (short*)ulds;            // [128][16] sh8 = 32KB
  short* w_t = (short*)(ulds + 32768);  // [128][16] sh8 = 32KB
  const int tid = threadIdx.x;
  const int wave = tid >> 6, lane = tid & 63;
  const int col = lane & 15, grp = lane >> 4;
  const size_t r0g = (size_t)blockIdx.x * 128;
  const int bb = (int)(r0g >> 10), s0 = (int)(r0g & 1023);

  // stage input + kmask
#pragma unroll
  for (int t = 0; t < 8; ++t) {
    const int u = t * 256 + tid, row = u >> 4, sl = u & 15;
    float s = 0.f;
    sh8 v = cvt8(in + (r0g + row) * 128 + sl * 8, s);
    *(sh8*)&a_t[(row * 16 + (sl ^ (row & 15))) * 8] = v;
    s += __shfl_xor(s, 1); s += __shfl_xor(s, 2);
    s += __shfl_xor(s, 4); s += __shfl_xor(s, 8);
    if ((lane & 15) == 0) km[r0g + row] = (s != 0.f) ? 1.f : 0.f;
  }
  // stage W phase A: rows 0..63 = Wk, 64..127 = Wv[0:64]
#pragma unroll
  for (int t = 0; t < 8; ++t) {
    const int u = t * 256 + tid, row = u >> 4, sl = u & 15;
    const float* src = (row < 64) ? (Wk + (size_t)row * 128) : (Wv + (size_t)(row - 64) * 128);
    float s = 0.f;
    sh8 v = cvt8(src + sl * 8, s);
    *(sh8*)&w_t[(row * 16 + (sl ^ (row & 15))) * 8] = v;
  }
  __syncthreads();

  const int r0 = wave * 32;
  sh8 a[2][4];
#pragma unroll
  for (int ri = 0; ri < 2; ++ri)
#pragma unroll
    for (int t = 0; t < 4; ++t) {
      const int row = r0 + ri * 16 + col;
      a[ri][t] = *(const sh8*)&a_t[(row * 16 + ((grp + 4 * t) ^ (row & 15))) * 8];
    }
  f4 acck[2][4], accv[2][8];
#pragma unroll
  for (int ri = 0; ri < 2; ++ri) {
#pragma unroll
    for (int jt = 0; jt < 4; ++jt) acck[ri][jt] = (f4)0.f;
#pragma unroll
    for (int jt = 0; jt < 8; ++jt) accv[ri][jt] = (f4)0.f;
  }
  // phase A: kit (jt 0..3) + V cols 0..63 (jt 4..7)
#pragma unroll
  for (int jt = 0; jt < 8; ++jt) {
    const int j = jt * 16 + col;
    sh8 bw[4];
#pragma unroll
    for (int t = 0; t < 4; ++t)
      bw[t] = *(const sh8*)&w_t[(j * 16 + ((grp + 4 * t) ^ (j & 15))) * 8];
#pragma unroll
    for (int ri = 0; ri < 2; ++ri)
#pragma unroll
      for (int t = 0; t < 4; ++t) {
        f4& dst = (jt < 4) ? acck[ri][jt] : accv[ri][jt - 4];
        dst = __builtin_amdgcn_mfma_f32_16x16x32_bf16(a[ri][t], bw[t], dst, 0, 0, 0);
      }
  }
  // store kit
#pragma unroll
  for (int jt = 0; jt < 4; ++jt) {
    const float bj = bk_[jt * 16 + col];
#pragma unroll
    for (int ri = 0; ri < 2; ++ri)
#pragma unroll
      for (int r = 0; r < 4; ++r)
        kit[(r0g + r0 + ri * 16 + grp * 4 + r) * 64 + jt * 16 + col] = f2bf(acck[ri][jt][r] + bj);
  }
  __syncthreads();
  // stage W phase B: rows 0..63 = Wv[64:128]
#pragma unroll
  for (int t = 0; t < 4; ++t) {
    const int u = t * 256 + tid, row = u >> 4, sl = u & 15;
    float s = 0.f;
    sh8 v = cvt8(Wv + (size_t)(64 + row) * 128 + sl * 8, s);
    *(sh8*)&w_t[(row * 16 + (sl ^ (row & 15))) * 8] = v;
  }
  __syncthreads();
  // phase B: V cols 64..127 (accv jt 4..7)
#pragma unroll
  for (int jt = 0; jt < 4; ++jt) {
    const int j = jt * 16 + col;
    sh8 bw[4];
#pragma unroll
    for (int t = 0; t < 4; ++t)
      bw[t] = *(const sh8*)&w_t[(j * 16 + ((grp + 4 * t) ^ (j & 15))) * 8];
#pragma unroll
    for (int ri = 0; ri < 2; ++ri)
#pragma unroll
      for (int t = 0; t < 4; ++t)
        accv[ri][4 + jt] = __builtin_amdgcn_mfma_f32_16x16x32_bf16(a[ri][t], bw[t], accv[ri][4 + jt], 0, 0, 0);
  }
  __syncthreads();  // all a_t/w_t reads done -> reuse as transpose tile
  // V transpose: vtile[j 0..127][s 0..127] (+pad 136) overlaying a_t/w_t
  short* vtile = (short*)ulds;
#pragma unroll
  for (int vjt = 0; vjt < 8; ++vjt) {
    const int j = vjt * 16 + col;
    const float bvj = bv_[j];
#pragma unroll
    for (int ri = 0; ri < 2; ++ri)
#pragma unroll
      for (int r = 0; r < 4; ++r)
        vtile[j * 136 + r0 + ri * 16 + grp * 4 + r] = f2bf(accv[ri][vjt][r] + bvj);
  }
  __syncthreads();
  const int j2 = tid >> 1, half = tid & 1;
  short* dst = vt + ((size_t)(bb * 128 + j2)) * S_N + s0 + half * 64;
#pragma unroll
  for (int i = 0; i < 8; ++i)
    *(sh8*)(dst + i * 8) = *(const sh8*)&vtile[j2 * 136 + half * 64 + i * 8];
}

// ---------- Phase 2: fused attention, depth-3 counted-vmcnt pipeline (R13, unchanged) ----------
__global__ __launch_bounds__(256, 2) void attn_kernel(
    const short* __restrict__ qit, const short* __restrict__ kit,
    const short* __restrict__ qctx, const short* __restrict__ kctx,
    const short* __restrict__ vt,     // [B,128,S] bf16
    const float* __restrict__ noise,  // [B,2,S,S]
    const float* __restrict__ sigma,  // [B,2]
    const float* __restrict__ qmask, const float* __restrict__ kmask,  // [B,S]
    const float* __restrict__ qin,    // queries_it [B,S,128]
    const float* __restrict__ W1, const float* __restrict__ b1,
    const float* __restrict__ W2, const float* __restrict__ b2,
    float* __restrict__ out) {
  __shared__ __align__(16) char bufs[4][16384];
  __shared__ float kml[1024];
  __shared__ float lsum_lds[4][2][16];

  const int tid = threadIdx.x;
  const int wave = tid >> 6, lane = tid & 63;
  const int bid = blockIdx.x;
  const int wg = ((bid & 7) << 6) | (bid >> 3);  // XCD swizzle (512 % 8 == 0)
  const int b = wg >> 4, qt = wg & 15;
  const int qblk = qt * 64;
  const int qbase = qblk + wave * 16;
  const int col = lane & 15, grp = lane >> 4;
  const int swk = col & 7;

  const float w100 = W1[0], w101 = W1[1], w110 = W1[2], w111 = W1[3];
  const float bb10 = b1[0], bb11 = b1[1];
  const float sc = 0.125f;
  const float w200 = W2[0] * sc, w201 = W2[1] * sc, w210 = W2[2] * sc, w211 = W2[3] * sc;
  const float bb20 = b2[0] * sc, bb21 = b2[1] * sc;
  float sg0 = sigma[b * 2 + 0]; sg0 *= sg0;
  float sg1 = sigma[b * 2 + 1]; sg1 *= sg1;

  const int qrow = qbase + col;
  sh8 aqit[2], aqctx[2];
#pragma unroll
  for (int t = 0; t < 2; ++t) {
    aqit[t] = *(const sh8*)(qit + ((size_t)(b * S_N + qrow)) * 64 + grp * 8 + t * 32);
    aqctx[t] = *(const sh8*)(qctx + ((size_t)(b * S_N + qrow)) * 64 + grp * 8 + t * 32);
  }

  f4 acc[2][4];
#pragma unroll
  for (int h = 0; h < 2; ++h)
#pragma unroll
    for (int dt = 0; dt < 4; ++dt) acc[h][dt] = (f4)0.f;
  float rs0 = 0.f, rs1 = 0.f;

  const float* nz_g = noise + (size_t)(b * 2) * S_N * S_N;
  const short* kit_g = kit + (size_t)b * S_N * 64;
  const short* kctx_g = kctx + (size_t)b * S_N * 64;
  const short* vt_g = vt + (size_t)b * 128 * S_N;

  for (int i = tid; i < 1024; i += 256) kml[i] = kmask[(size_t)b * S_N + i];

  auto STAGE = [&](char* buf, int kc) {
    if (wave == 0) {
#pragma unroll
      for (int j = 0; j < 2; ++j) {
        const int u = j * 64 + lane, row = u >> 3, sl = u & 7;
        const size_t off = (size_t)(kc + row) * 64 + ((sl ^ (row & 7)) << 3);
        __builtin_amdgcn_global_load_lds((const AS1 unsigned*)(kit_g + off),
                                         (AS3 unsigned*)(buf + j * 1024), 16, 0, 0);
        __builtin_amdgcn_global_load_lds((const AS1 unsigned*)(kctx_g + off),
                                         (AS3 unsigned*)(buf + 2048 + j * 1024), 16, 0, 0);
      }
    } else if (wave == 1) {
#pragma unroll
      for (int j = 0; j < 4; ++j) {
        const int u = j * 64 + lane, d = u >> 1, sl = u & 1;
        const short* g = vt_g + (size_t)d * S_N + kc + ((sl ^ (d & 1)) << 3);
        __builtin_amdgcn_global_load_lds((const AS1 unsigned*)g,
                                         (AS3 unsigned*)(buf + 4096 + j * 1024), 16, 0, 0);
      }
    } else {
#pragma unroll
      for (int j = 0; j < 4; ++j) {
        const int un = (wave - 2) * 4 + j;
        const int u = un * 64 + lane, r = u >> 2, head = r >> 6, q = r & 63, sl = u & 3;
        const float* g = nz_g + (size_t)head * S_N * S_N + (size_t)(qblk + q) * S_N + kc +
                         ((sl ^ (q & 3)) << 2);
        __builtin_amdgcn_global_load_lds((const AS1 unsigned*)g,
                                         (AS3 unsigned*)(buf + 8192 + un * 1024), 16, 0, 0);
      }
    }
  };

  STAGE(bufs[0], 0);
  STAGE(bufs[1], 16);
  STAGE(bufs[2], 32);

#pragma unroll 1
  for (int k = 0; k < 64; ++k) {
    asm volatile("s_waitcnt vmcnt(8)" ::: "memory");
    __builtin_amdgcn_sched_barrier(0);
    __builtin_amdgcn_s_barrier();
    STAGE(bufs[(k + 3) & 3], ((k + 3) & 63) * 16);

    const char* cur = bufs[k & 3];
    const short* Kb = (const short*)cur;
    const short* Cb = (const short*)(cur + 2048);
    const short* Vb = (const short*)(cur + 4096);
    const float* Nb = (const float*)(cur + 8192);

    f4 sit = (f4)0.f, sctx = (f4)0.f;
#pragma unroll
    for (int t = 0; t < 2; ++t) {
      const int so = ((grp + 4 * t) ^ swk) * 8;
      sh8 bk = *(const sh8*)&Kb[col * 64 + so];
      sit = __builtin_amdgcn_mfma_f32_16x16x32_bf16(bk, aqit[t], sit, 0, 0, 0);
      sh8 bc = *(const sh8*)&Cb[col * 64 + so];
      sctx = __builtin_amdgcn_mfma_f32_16x16x32_bf16(bc, aqctx[t], sctx, 0, 0, 0);
    }
    const int qrl = wave * 16 + col;
    const int nso = (grp ^ (col & 3)) << 2;
    f4 n0 = *(const f4*)&Nb[qrl * 16 + nso];
    f4 n1 = *(const f4*)&Nb[(64 + qrl) * 16 + nso];
    f4 km = *(const f4*)&kml[k * 16 + grp * 4];
    sh4 po, pc;
#pragma unroll
    for (int r = 0; r < 4; ++r) {
      float x0 = fmaf(n0[r], sg0, sit[r]);
      float x1 = fmaf(n1[r], sg1, sctx[r]);
      float h0 = fmaxf(fmaf(w101, x1, fmaf(w100, x0, bb10)), 0.f);
      float h1 = fmaxf(fmaf(w111, x1, fmaf(w110, x0, bb11)), 0.f);
      float L0 = fmaf(w201, h1, fmaf(w200, h0, bb20));
      float L1 = fmaf(w211, h1, fmaf(w210, h0, bb21));
      float p0 = __expf(L0) * km[r];
      float p1 = __expf(L1) * km[r];
      rs0 += p0;
      rs1 += p1;
      po[r] = f2bf(p0);
      pc[r] = f2bf(p1);
    }
#pragma unroll
    for (int h = 0; h < 2; ++h) {
      const sh4 pa = h ? pc : po;
#pragma unroll
      for (int dt = 0; dt < 4; ++dt) {
        const int drow = h * 64 + dt * 16 + col;
        const int phys = (grp >> 1) ^ (drow & 1);
        sh4 bv = *(const sh4*)&Vb[drow * 16 + phys * 8 + (grp & 1) * 4];
        acc[h][dt] = mfma16(pa, bv, acc[h][dt]);
      }
    }
  }

  rs0 += __shfl_xor(rs0, 16); rs0 += __shfl_xor(rs0, 32);
  rs1 += __shfl_xor(rs1, 16); rs1 += __shfl_xor(rs1, 32);
  if (lane < 16) {
    lsum_lds[wave][0][col] = rs0;
    lsum_lds[wave][1][col] = rs1;
  }
  __syncthreads();
  f4 ls0 = *(const f4*)&lsum_lds[wave][0][grp * 4];
  f4 ls1 = *(const f4*)&lsum_lds[wave][1][grp * 4];
  f4 qm4 = *(const f4*)(qmask + (size_t)b * S_N + qbase + grp * 4);
#pragma unroll
  for (int h = 0; h < 2; ++h)
#pragma unroll
    for (int dt = 0; dt < 4; ++dt)
#pragma unroll
      for (int r = 0; r < 4; ++r) {
        const float s2 = qm4[r] / (h ? ls1[r] : ls0[r]);
        const size_t o = ((size_t)(b * S_N + qbase + grp * 4 + r)) * 128 + h * 64 + dt * 16 + col;
        out[o] = acc[h][dt][r] * s2 + qin[o];
      }
}

extern "C" void kernel_launch(void* const* d_in, const int* in_sizes, int n_in,
                              void* d_out, int out_size, void* d_ws, size_t ws_size,
                              hipStream_t stream) {
  const float* queries_it = (const float*)d_in[0];
  const float* queries_ctx = (const float*)d_in[1];
  const float* keys_it = (const float*)d_in[2];
  const float* keys_ctx = (const float*)d_in[3];
  const float* sigma = (const float*)d_in[4];
  const float* noise = (const float*)d_in[5];
  const float* Wq_it = (const float*)d_in[6];
  const float* bq_it = (const float*)d_in[7];
  const float* Wk_it = (const float*)d_in[8];
  const float* bk_it = (const float*)d_in[9];
  const float* Wq_ctx = (const float*)d_in[10];
  const float* bq_ctx = (const float*)d_in[11];
  const float* Wk_ctx = (const float*)d_in[12];
  const float* bk_ctx = (const float*)d_in[13];
  const float* Wv = (const float*)d_in[14];
  const float* bv = (const float*)d_in[15];
  const float* W1 = (const float*)d_in[16];
  const float* b1 = (const float*)d_in[17];
  const float* W2 = (const float*)d_in[18];
  const float* b2 = (const float*)d_in[19];
  float* out = (float*)d_out;

  char* ws = (char*)d_ws;
  short* qit = (short*)(ws);                    // 4 MB
  short* kit = (short*)(ws + (4ull << 20));     // 4 MB
  short* qctx = (short*)(ws + (8ull << 20));    // 4 MB
  short* kctx = (short*)(ws + (12ull << 20));   // 4 MB
  short* vt = (short*)(ws + (16ull << 20));     // 8 MB  [B,128,S]
  float* qmask = (float*)(ws + (24ull << 20));  // 128 KB
  float* kmask = (float*)(ws + (24ull << 20) + (size_t)B_N * S_N * 4);

  const int NB = B_N * S_N / 128;  // 256 blocks per projection
  proj_mfma<128, true><<<dim3(NB), 256, 0, stream>>>(queries_it, Wq_it, bq_it, qit, qmask);
  proj_k_mfma<<<dim3(NB), 256, 0, stream>>>(keys_it, Wk_it, bk_it, Wv, bv, kit, vt, kmask);
  proj_mfma<64, false><<<dim3(NB), 256, 0, stream>>>(queries_ctx, Wq_ctx, bq_ctx, qctx, nullptr);
  proj_mfma<64, false><<<dim3(NB), 256, 0, stream>>>(keys_ctx, Wk_ctx, bk_ctx, kctx, nullptr);

  attn_kernel<<<dim3(B_N * (S_N / 64)), 256, 0, stream>>>(
      qit, kit, qctx, kctx, vt, noise, sigma, qmask, kmask, queries_it,
      W1, b1, W2, b2, out);
}